// Round 1
// baseline (10915.918 us; speedup 1.0000x reference)
//
#include <hip/hip_runtime.h>
#include <hip/hip_bf16.h>
#include <math.h>

#define TT 512
#define BB 4096
#define IN_DIM 12
#define HH 32
#define LL 10
#define CC 4
#define BC 8          // batch elements per block
#define NTHREADS 192  // 96 gate rows x 2 batch halves

__device__ __forceinline__ float sigmoidf_(float x) {
    return 1.0f / (1.0f + __expf(-x));
}
__device__ __forceinline__ float tanhf_(float x) {
    float ax = fabsf(x);
    float e  = __expf(-2.0f * ax);
    float t  = (1.0f - e) / (1.0f + e);
    return copysignf(t, x);
}

// One GRU layer over all T timesteps for a batch chunk of BC.
// Thread (g, bhalf): owns full weight row g (KIN inp weights + 32 hidden
// weights) in registers; computes gates for 4 batch elements.
template<int KIN, bool FIRST, bool LAST>
__global__ __launch_bounds__(NTHREADS)
void gru_layer(const float* in,          // FIRST ? x [T][B][12] : buf [T][B][32]
               float* buf,               // out [T][B][32] (in-place ok)
               const float* __restrict__ Wi,   // [96][KIN]
               const float* __restrict__ Wh,   // [96][32]
               const float* __restrict__ bi,   // [96]
               const float* __restrict__ bh,   // [96]
               const int*   __restrict__ lengths,
               float*       __restrict__ last) // [B][32]
{
    constexpr int K = KIN + HH;
    __shared__ float cat[K][BC];     // [k][b]; rows 0..KIN-1 = input, KIN.. = h
    __shared__ float Gr [HH][BC];
    __shared__ float Gz [HH][BC];
    __shared__ float Gin[HH][BC];
    __shared__ float Ghn[HH][BC];

    const int tid  = threadIdx.x;
    const int bblk = blockIdx.x * BC;

    const int g  = (tid < 96) ? tid : tid - 96;
    const int b4 = (tid < 96) ? 0 : 4;

    // stationary weights in registers
    float w[K];
#pragma unroll
    for (int k = 0; k < KIN; k++) w[k] = Wi[g * KIN + k];
#pragma unroll
    for (int k = 0; k < HH; k++)  w[KIN + k] = Wh[g * HH + k];
    const float bii = bi[g];
    const float bhh = bh[g];

    // h = 0
    for (int i = tid; i < HH * BC; i += NTHREADS)
        cat[KIN + (i >> 3)][i & 7] = 0.0f;

    // stage input for t = 0
    if (FIRST) {
        if (tid < BC * IN_DIM) {
            float v = in[(size_t)0 * BB * IN_DIM + (size_t)bblk * IN_DIM + tid];
            cat[tid % IN_DIM][tid / IN_DIM] = v;
        }
    } else {
        for (int i = tid; i < BC * HH; i += NTHREADS) {
            float v = in[(size_t)0 * BB * HH + (size_t)bblk * HH + i];
            cat[i & 31][i >> 5] = v;
        }
    }

    for (int t = 0; t < TT; t++) {
        __syncthreads();   // input staged + h updated -> visible to dots

        // --- gate dot products: thread owns row g, 4 batch elements ---
        float ai0 = bii, ai1 = bii, ai2 = bii, ai3 = bii;
        float ah0 = bhh, ah1 = bhh, ah2 = bhh, ah3 = bhh;
#pragma unroll
        for (int k = 0; k < KIN; k++) {
            float4 v = *(const float4*)&cat[k][b4];
            ai0 = fmaf(w[k], v.x, ai0);
            ai1 = fmaf(w[k], v.y, ai1);
            ai2 = fmaf(w[k], v.z, ai2);
            ai3 = fmaf(w[k], v.w, ai3);
        }
#pragma unroll
        for (int k = 0; k < HH; k++) {
            float4 v = *(const float4*)&cat[KIN + k][b4];
            ah0 = fmaf(w[KIN + k], v.x, ah0);
            ah1 = fmaf(w[KIN + k], v.y, ah1);
            ah2 = fmaf(w[KIN + k], v.z, ah2);
            ah3 = fmaf(w[KIN + k], v.w, ah3);
        }
        if (g < HH) {
            *(float4*)&Gr[g][b4] =
                make_float4(ai0 + ah0, ai1 + ah1, ai2 + ah2, ai3 + ah3);
        } else if (g < 2 * HH) {
            *(float4*)&Gz[g - HH][b4] =
                make_float4(ai0 + ah0, ai1 + ah1, ai2 + ah2, ai3 + ah3);
        } else {
            *(float4*)&Gin[g - 2 * HH][b4] = make_float4(ai0, ai1, ai2, ai3);
            *(float4*)&Ghn[g - 2 * HH][b4] = make_float4(ah0, ah1, ah2, ah3);
        }
        __syncthreads();   // gates visible; dots done reading cat

        // --- combine: new h, write output --- (plus stage next input)
        for (int i = tid; i < BC * HH; i += NTHREADS) {
            int b = i >> 5, j = i & 31;
            float r  = sigmoidf_(Gr[j][b]);
            float z  = sigmoidf_(Gz[j][b]);
            float n  = tanhf_(fmaf(r, Ghn[j][b], Gin[j][b]));
            float hp = cat[KIN + j][b];
            float hn = (1.0f - z) * n + z * hp;
            cat[KIN + j][b] = hn;
            if (!LAST) {
                buf[(size_t)t * BB * HH + (size_t)(bblk + b) * HH + j] = hn;
            } else {
                int len = lengths[bblk + b];
                if (len < 1) len = 1;
                if (t == len - 1) last[(size_t)(bblk + b) * HH + j] = hn;
            }
        }

        // stage input for t+1 (disjoint LDS region from combine's writes)
        if (t + 1 < TT) {
            if (FIRST) {
                if (tid < BC * IN_DIM) {
                    float v = in[(size_t)(t + 1) * BB * IN_DIM +
                                 (size_t)bblk * IN_DIM + tid];
                    cat[tid % IN_DIM][tid / IN_DIM] = v;
                }
            } else {
                for (int i = tid; i < BC * HH; i += NTHREADS) {
                    float v = in[(size_t)(t + 1) * BB * HH +
                                 (size_t)bblk * HH + i];
                    cat[i & 31][i >> 5] = v;
                }
            }
        }
    }
}

__global__ __launch_bounds__(256)
void fc_head(const float* __restrict__ last,
             const float* __restrict__ fcW,   // [C][H]
             const float* __restrict__ fcb,   // [C]
             float* __restrict__ out)         // [B][C]
{
    int b = blockIdx.x * blockDim.x + threadIdx.x;
    if (b >= BB) return;
    float lg[CC];
#pragma unroll
    for (int c = 0; c < CC; c++) lg[c] = fcb[c];
#pragma unroll
    for (int j = 0; j < HH; j++) {
        float h = last[(size_t)b * HH + j];
#pragma unroll
        for (int c = 0; c < CC; c++) lg[c] = fmaf(fcW[c * HH + j], h, lg[c]);
    }
    float m = lg[0];
#pragma unroll
    for (int c = 1; c < CC; c++) m = fmaxf(m, lg[c]);
    float s = 0.0f;
#pragma unroll
    for (int c = 0; c < CC; c++) s += __expf(lg[c] - m);
    float lse = m + logf(s);
#pragma unroll
    for (int c = 0; c < CC; c++) out[(size_t)b * CC + c] = lg[c] - lse;
}

extern "C" void kernel_launch(void* const* d_in, const int* in_sizes, int n_in,
                              void* d_out, int out_size, void* d_ws, size_t ws_size,
                              hipStream_t stream)
{
    const float* x    = (const float*)d_in[0];
    const float* Wih0 = (const float*)d_in[1];
    const float* Whh0 = (const float*)d_in[2];
    const float* bih0 = (const float*)d_in[3];
    const float* bhh0 = (const float*)d_in[4];
    const float* Wih  = (const float*)d_in[5];   // [9][96][32]
    const float* Whh  = (const float*)d_in[6];   // [9][96][32]
    const float* bih  = (const float*)d_in[7];   // [9][96]
    const float* bhh  = (const float*)d_in[8];   // [9][96]
    const float* fcW  = (const float*)d_in[9];
    const float* fcb  = (const float*)d_in[10];
    const int*   lens = (const int*)d_in[11];
    float* out = (float*)d_out;

    float* buf  = (float*)d_ws;                       // [T][B][H] = 256 MB
    float* last = buf + (size_t)TT * BB * HH;         // [B][H]

    dim3 grid(BB / BC), blk(NTHREADS);

    // layer 0: x -> buf
    gru_layer<IN_DIM, true, false><<<grid, blk, 0, stream>>>(
        x, buf, Wih0, Whh0, bih0, bhh0, nullptr, nullptr);

    // layers 1..8: buf -> buf (in-place per (t,b) slot)
    for (int l = 1; l <= 8; l++) {
        gru_layer<HH, false, false><<<grid, blk, 0, stream>>>(
            buf, buf,
            Wih + (size_t)(l - 1) * 96 * HH,
            Whh + (size_t)(l - 1) * 96 * HH,
            bih + (size_t)(l - 1) * 96,
            bhh + (size_t)(l - 1) * 96,
            nullptr, nullptr);
    }

    // layer 9: buf -> last (no full output write)
    gru_layer<HH, false, true><<<grid, blk, 0, stream>>>(
        buf, buf,
        Wih + (size_t)8 * 96 * HH,
        Whh + (size_t)8 * 96 * HH,
        bih + (size_t)8 * 96,
        bhh + (size_t)8 * 96,
        lens, last);

    // FC + log_softmax
    fc_head<<<dim3(BB / 256), dim3(256), 0, stream>>>(last, fcW, fcb, out);
}

// Round 2
// 8450.320 us; speedup vs baseline: 1.2918x; 1.2918x over previous
//
#include <hip/hip_runtime.h>
#include <hip/hip_bf16.h>
#include <math.h>

#define TT 512
#define BB 4096
#define IN_DIM 12
#define HH 32
#define LL 10
#define CC 4

__device__ __forceinline__ float sigmoidf_(float x) {
    return 1.0f / (1.0f + __expf(-x));
}
__device__ __forceinline__ float tanhf_(float x) {
    float ax = fabsf(x);
    float e  = __expf(-2.0f * ax);
    float t  = (1.0f - e) / (1.0f + e);
    return copysignf(t, x);
}

// Wave-autonomous GRU layer: one wave (64 lanes) owns one batch element for
// all T timesteps. Lane (j = lane&31, kh = lane>>5):
//   kh=0 accumulates the input-side partials (Wi rows, k in [0,KIN))
//   kh=1 accumulates the hidden-side partials (Wh rows, k in [0,32))
// 96 stationary weights per lane in VGPRs. cat[64] = [x_t | h] lives in
// wave-private LDS. No __syncthreads anywhere: wave lockstep + compiler
// lgkmcnt waits give the ordering.
template<int KIN, bool FIRST, bool LAST>
__global__ __launch_bounds__(256, 3)
void gru_layer(const float* __restrict__ in,     // FIRST ? x [T][B][12] : buf [T][B][32]
               float* __restrict__ outbuf,       // [T][B][32] (in-place with in is safe)
               const float* __restrict__ Wi,     // [96][KIN]
               const float* __restrict__ Wh,     // [96][32]
               const float* __restrict__ bi,     // [96]
               const float* __restrict__ bh,     // [96]
               const int*   __restrict__ lengths,
               float*       __restrict__ last)   // [B][32]
{
    __shared__ float cat[4][2 * HH];   // per-wave: [0..31]=x_t, [32..63]=h

    const int tid  = threadIdx.x;
    const int w    = tid >> 6;
    const int lane = tid & 63;
    const int j    = lane & 31;
    const int kh   = lane >> 5;
    const int b    = blockIdx.x * 4 + w;
    float* mycat = cat[w];

    // ---- stationary weights (3 gate rows) into registers ----
    float wr[HH], wz[HH], wn[HH];
    if constexpr (KIN == HH) {
        const float* Wsel = kh ? Wh : Wi;
#pragma unroll
        for (int k = 0; k < HH; k++) {
            wr[k] = Wsel[(0 * HH + j) * HH + k];
            wz[k] = Wsel[(1 * HH + j) * HH + k];
            wn[k] = Wsel[(2 * HH + j) * HH + k];
        }
    } else {
        if (kh == 0) {
#pragma unroll
            for (int k = 0; k < KIN; k++) {
                wr[k] = Wi[(0 * HH + j) * KIN + k];
                wz[k] = Wi[(1 * HH + j) * KIN + k];
                wn[k] = Wi[(2 * HH + j) * KIN + k];
            }
        } else {
#pragma unroll
            for (int k = 0; k < HH; k++) {
                wr[k] = Wh[(0 * HH + j) * HH + k];
                wz[k] = Wh[(1 * HH + j) * HH + k];
                wn[k] = Wh[(2 * HH + j) * HH + k];
            }
        }
    }
    const float br = kh ? bh[0 * HH + j] : bi[0 * HH + j];
    const float bz = kh ? bh[1 * HH + j] : bi[1 * HH + j];
    const float bn = kh ? bh[2 * HH + j] : bi[2 * HH + j];

    int lastT = TT;  // for LAST layer: t == lastT-1 triggers the capture
    if (LAST) {
        int len = lengths[b];
        lastT = (len < 1) ? 1 : len;
    }

    // h0 = 0 in LDS; prefetch x_0
    if (kh == 0) mycat[HH + j] = 0.0f;
    float xreg = 0.0f;
    if (FIRST) {
        if (kh == 0 && j < IN_DIM)
            xreg = in[((size_t)0 * BB + b) * IN_DIM + j];
    } else {
        if (kh == 0)
            xreg = in[((size_t)0 * BB + b) * HH + j];
    }
    float hprev = 0.0f;

    for (int t = 0; t < TT; t++) {
        // stage x_t (kh=0 half writes; whole wave reads after compiler wait)
        if (kh == 0) {
            if (!FIRST || j < IN_DIM) mycat[j] = xreg;
        }
        // prefetch x_{t+1}
        if (t + 1 < TT) {
            if (FIRST) {
                if (kh == 0 && j < IN_DIM)
                    xreg = in[((size_t)(t + 1) * BB + b) * IN_DIM + j];
            } else {
                if (kh == 0)
                    xreg = in[((size_t)(t + 1) * BB + b) * HH + j];
            }
        }

        // ---- gate dot products ----
        float accr = br, accz = bz, accn = bn;
        if constexpr (KIN == HH) {
            const float* base = mycat + (kh ? HH : 0);
#pragma unroll
            for (int k0 = 0; k0 < HH; k0 += 4) {
                float4 v = *(const float4*)(base + k0);
                accr = fmaf(wr[k0 + 0], v.x, accr);
                accz = fmaf(wz[k0 + 0], v.x, accz);
                accn = fmaf(wn[k0 + 0], v.x, accn);
                accr = fmaf(wr[k0 + 1], v.y, accr);
                accz = fmaf(wz[k0 + 1], v.y, accz);
                accn = fmaf(wn[k0 + 1], v.y, accn);
                accr = fmaf(wr[k0 + 2], v.z, accr);
                accz = fmaf(wz[k0 + 2], v.z, accz);
                accn = fmaf(wn[k0 + 2], v.z, accn);
                accr = fmaf(wr[k0 + 3], v.w, accr);
                accz = fmaf(wz[k0 + 3], v.w, accz);
                accn = fmaf(wn[k0 + 3], v.w, accn);
            }
        } else {
            if (kh == 0) {
#pragma unroll
                for (int k0 = 0; k0 < KIN; k0 += 4) {
                    float4 v = *(const float4*)(mycat + k0);
                    accr = fmaf(wr[k0 + 0], v.x, accr);
                    accz = fmaf(wz[k0 + 0], v.x, accz);
                    accn = fmaf(wn[k0 + 0], v.x, accn);
                    accr = fmaf(wr[k0 + 1], v.y, accr);
                    accz = fmaf(wz[k0 + 1], v.y, accz);
                    accn = fmaf(wn[k0 + 1], v.y, accn);
                    accr = fmaf(wr[k0 + 2], v.z, accr);
                    accz = fmaf(wz[k0 + 2], v.z, accz);
                    accn = fmaf(wn[k0 + 2], v.z, accn);
                    accr = fmaf(wr[k0 + 3], v.w, accr);
                    accz = fmaf(wz[k0 + 3], v.w, accz);
                    accn = fmaf(wn[k0 + 3], v.w, accn);
                }
            } else {
#pragma unroll
                for (int k0 = 0; k0 < HH; k0 += 4) {
                    float4 v = *(const float4*)(mycat + HH + k0);
                    accr = fmaf(wr[k0 + 0], v.x, accr);
                    accz = fmaf(wz[k0 + 0], v.x, accz);
                    accn = fmaf(wn[k0 + 0], v.x, accn);
                    accr = fmaf(wr[k0 + 1], v.y, accr);
                    accz = fmaf(wz[k0 + 1], v.y, accz);
                    accn = fmaf(wn[k0 + 1], v.y, accn);
                    accr = fmaf(wr[k0 + 2], v.z, accr);
                    accz = fmaf(wz[k0 + 2], v.z, accz);
                    accn = fmaf(wn[k0 + 2], v.z, accn);
                    accr = fmaf(wr[k0 + 3], v.w, accr);
                    accz = fmaf(wz[k0 + 3], v.w, accz);
                    accn = fmaf(wn[k0 + 3], v.w, accn);
                }
            }
        }

        // ---- combine halves (i-part at kh=0, h-part at kh=1) ----
        float orr = __shfl_xor(accr, 32);
        float oz  = __shfl_xor(accz, 32);
        float on  = __shfl_xor(accn, 32);
        float rfull = accr + orr;
        float zfull = accz + oz;
        float i_n = kh ? on   : accn;
        float h_n = kh ? accn : on;

        float r = sigmoidf_(rfull);
        float z = sigmoidf_(zfull);
        float n = tanhf_(fmaf(r, h_n, i_n));
        float hnew = n + z * (hprev - n);
        hprev = hnew;

        if (kh == 0) {
            mycat[HH + j] = hnew;           // h for next step (read by kh=1 half)
            if (!LAST) {
                outbuf[((size_t)t * BB + b) * HH + j] = hnew;
            } else {
                if (t == lastT - 1) last[(size_t)b * HH + j] = hnew;
            }
        }
    }
}

__global__ __launch_bounds__(256)
void fc_head(const float* __restrict__ last,
             const float* __restrict__ fcW,   // [C][H]
             const float* __restrict__ fcb,   // [C]
             float* __restrict__ out)         // [B][C]
{
    int b = blockIdx.x * blockDim.x + threadIdx.x;
    if (b >= BB) return;
    float lg[CC];
#pragma unroll
    for (int c = 0; c < CC; c++) lg[c] = fcb[c];
#pragma unroll
    for (int j = 0; j < HH; j++) {
        float h = last[(size_t)b * HH + j];
#pragma unroll
        for (int c = 0; c < CC; c++) lg[c] = fmaf(fcW[c * HH + j], h, lg[c]);
    }
    float m = lg[0];
#pragma unroll
    for (int c = 1; c < CC; c++) m = fmaxf(m, lg[c]);
    float s = 0.0f;
#pragma unroll
    for (int c = 0; c < CC; c++) s += __expf(lg[c] - m);
    float lse = m + logf(s);
#pragma unroll
    for (int c = 0; c < CC; c++) out[(size_t)b * CC + c] = lg[c] - lse;
}

extern "C" void kernel_launch(void* const* d_in, const int* in_sizes, int n_in,
                              void* d_out, int out_size, void* d_ws, size_t ws_size,
                              hipStream_t stream)
{
    const float* x    = (const float*)d_in[0];
    const float* Wih0 = (const float*)d_in[1];
    const float* Whh0 = (const float*)d_in[2];
    const float* bih0 = (const float*)d_in[3];
    const float* bhh0 = (const float*)d_in[4];
    const float* Wih  = (const float*)d_in[5];   // [9][96][32]
    const float* Whh  = (const float*)d_in[6];   // [9][96][32]
    const float* bih  = (const float*)d_in[7];   // [9][96]
    const float* bhh  = (const float*)d_in[8];   // [9][96]
    const float* fcW  = (const float*)d_in[9];
    const float* fcb  = (const float*)d_in[10];
    const int*   lens = (const int*)d_in[11];
    float* out = (float*)d_out;

    float* buf  = (float*)d_ws;                       // [T][B][H] = 256 MB
    float* last = buf + (size_t)TT * BB * HH;         // [B][H]

    dim3 grid(BB / 4), blk(256);   // 4 waves/block, 1 batch elem per wave

    gru_layer<IN_DIM, true, false><<<grid, blk, 0, stream>>>(
        x, buf, Wih0, Whh0, bih0, bhh0, nullptr, nullptr);

    for (int l = 1; l <= 8; l++) {
        gru_layer<HH, false, false><<<grid, blk, 0, stream>>>(
            buf, buf,
            Wih + (size_t)(l - 1) * 96 * HH,
            Whh + (size_t)(l - 1) * 96 * HH,
            bih + (size_t)(l - 1) * 96,
            bhh + (size_t)(l - 1) * 96,
            nullptr, nullptr);
    }

    gru_layer<HH, false, true><<<grid, blk, 0, stream>>>(
        buf, buf,
        Wih + (size_t)8 * 96 * HH,
        Whh + (size_t)8 * 96 * HH,
        bih + (size_t)8 * 96,
        bhh + (size_t)8 * 96,
        lens, last);

    fc_head<<<dim3(BB / 256), dim3(256), 0, stream>>>(last, fcW, fcb, out);
}

// Round 3
// 7413.752 us; speedup vs baseline: 1.4724x; 1.1398x over previous
//
#include <hip/hip_runtime.h>
#include <hip/hip_bf16.h>
#include <math.h>

#define TT 512
#define BB 4096
#define IN_DIM 12
#define HH 32
#define LL 10
#define CC 4
#define NTH (LL * 64)   // 640 threads = 10 waves, one per layer

__device__ __forceinline__ float sigmoidf_(float x) {
    return 1.0f / (1.0f + __expf(-x));
}
// branch-free tanh: 1 - 2/(e^{2x}+1); saturates correctly at +/-inf
__device__ __forceinline__ float tanhf_(float x) {
    float e = __expf(2.0f * x);
    return 1.0f - 2.0f / (e + 1.0f);
}

// Fused 10-layer GRU, temporally pipelined. Block = 10 waves = 1 batch elem.
// Wave w runs layer w; at tick, wave w computes its timestep t = tick - w.
// Inter-layer handoff via double-buffered LDS slots, 1 barrier per tick.
// Within a wave: lane (j = lane&31, kh = lane>>5); kh=0 accumulates the
// input-side partial, kh=1 the hidden-side partial; __shfl_xor(32) combines.
// Layer 0's Wi is zero-padded 12->32 so all waves run identical code.
__global__ __launch_bounds__(NTH, 1)
void gru_fused(const float* __restrict__ x,      // [T][B][12]
               const float* __restrict__ Wih0,   // [96][12]
               const float* __restrict__ Whh0,   // [96][32]
               const float* __restrict__ bih0,   // [96]
               const float* __restrict__ bhh0,   // [96]
               const float* __restrict__ Wih,    // [9][96][32]
               const float* __restrict__ Whh,    // [9][96][32]
               const float* __restrict__ bih,    // [9][96]
               const float* __restrict__ bhh,    // [9][96]
               const int*   __restrict__ lengths,
               float*       __restrict__ last)   // [B][32]
{
    __shared__ __align__(16) float hand[LL - 1][2][HH]; // layer l -> l+1, x2 buf
    __shared__ __align__(16) float hown[LL][HH];        // each wave's own h
    __shared__ __align__(16) float x0[HH];              // wave 0 staged x (pad 0)

    const int tid  = threadIdx.x;
    const int w    = tid >> 6;     // layer index
    const int lane = tid & 63;
    const int j    = lane & 31;
    const int kh   = lane >> 5;
    const int b    = blockIdx.x;

    // ---- per-wave weight pointers ----
    const float *Wi, *Wh, *bi, *bh;
    if (w == 0) { Wi = Wih0; Wh = Whh0; bi = bih0; bh = bhh0; }
    else {
        Wi = Wih + (size_t)(w - 1) * 96 * HH;
        Wh = Whh + (size_t)(w - 1) * 96 * HH;
        bi = bih + (size_t)(w - 1) * 96;
        bh = bhh + (size_t)(w - 1) * 96;
    }

    // ---- stationary weights (3 gate rows) in registers ----
    float wr[HH], wz[HH], wn[HH];
    if (kh == 0) {
        if (w == 0) {
#pragma unroll
            for (int k = 0; k < HH; k++) {
                wr[k] = (k < IN_DIM) ? Wi[(0 * HH + j) * IN_DIM + k] : 0.0f;
                wz[k] = (k < IN_DIM) ? Wi[(1 * HH + j) * IN_DIM + k] : 0.0f;
                wn[k] = (k < IN_DIM) ? Wi[(2 * HH + j) * IN_DIM + k] : 0.0f;
            }
        } else {
#pragma unroll
            for (int k = 0; k < HH; k++) {
                wr[k] = Wi[(0 * HH + j) * HH + k];
                wz[k] = Wi[(1 * HH + j) * HH + k];
                wn[k] = Wi[(2 * HH + j) * HH + k];
            }
        }
    } else {
#pragma unroll
        for (int k = 0; k < HH; k++) {
            wr[k] = Wh[(0 * HH + j) * HH + k];
            wz[k] = Wh[(1 * HH + j) * HH + k];
            wn[k] = Wh[(2 * HH + j) * HH + k];
        }
    }
    const float br = kh ? bh[0 * HH + j] : bi[0 * HH + j];
    const float bz = kh ? bh[1 * HH + j] : bi[1 * HH + j];
    const float bn = kh ? bh[2 * HH + j] : bi[2 * HH + j];

    int lastT = TT + 2;   // sentinel: never fires for w < LL-1
    if (w == LL - 1) {
        int len = lengths[b];
        lastT = (len < 1) ? 1 : len;
    }

    // ---- init ----
    if (kh == 0) hown[w][j] = 0.0f;
    if (w == 0 && kh == 0 && j >= IN_DIM) x0[j] = 0.0f;   // pad once
    float xreg = 0.0f;
    if (w == 0 && kh == 0 && j < IN_DIM)
        xreg = x[(size_t)0 * BB * IN_DIM + (size_t)b * IN_DIM + j];
    float hprev = 0.0f;
    __syncthreads();

    for (int tick = 0; tick < TT + LL - 1; tick++) {
        const int t = tick - w;
        if (t >= 0 && t < TT) {
            const float* inbase;
            if (w == 0) {
                if (kh == 0 && j < IN_DIM) x0[j] = xreg;   // stage x_t
                inbase = x0;
                if (kh == 0 && j < IN_DIM && t + 1 < TT)   // prefetch x_{t+1}
                    xreg = x[(size_t)(t + 1) * BB * IN_DIM +
                             (size_t)b * IN_DIM + j];
            } else {
                inbase = hand[w - 1][t & 1];   // producer wrote last tick
            }
            const float* base = kh ? hown[w] : inbase;

            float accr = br, accz = bz, accn = bn;
#pragma unroll
            for (int k0 = 0; k0 < HH; k0 += 4) {
                float4 v = *(const float4*)(base + k0);
                accr = fmaf(wr[k0 + 0], v.x, accr);
                accz = fmaf(wz[k0 + 0], v.x, accz);
                accn = fmaf(wn[k0 + 0], v.x, accn);
                accr = fmaf(wr[k0 + 1], v.y, accr);
                accz = fmaf(wz[k0 + 1], v.y, accz);
                accn = fmaf(wn[k0 + 1], v.y, accn);
                accr = fmaf(wr[k0 + 2], v.z, accr);
                accz = fmaf(wz[k0 + 2], v.z, accz);
                accn = fmaf(wn[k0 + 2], v.z, accn);
                accr = fmaf(wr[k0 + 3], v.w, accr);
                accz = fmaf(wz[k0 + 3], v.w, accz);
                accn = fmaf(wn[k0 + 3], v.w, accn);
            }

            float orr = __shfl_xor(accr, 32);
            float oz  = __shfl_xor(accz, 32);
            float on  = __shfl_xor(accn, 32);
            float r   = sigmoidf_(accr + orr);
            float z   = sigmoidf_(accz + oz);
            float i_n = kh ? on   : accn;
            float h_n = kh ? accn : on;
            float n   = tanhf_(fmaf(r, h_n, i_n));
            float hnew = fmaf(z, hprev - n, n);
            hprev = hnew;

            if (kh == 0) {
                hown[w][j] = hnew;                       // own next-step h
                if (w < LL - 1) {
                    hand[w][t & 1][j] = hnew;            // feed layer w+1
                } else if (t == lastT - 1) {
                    last[(size_t)b * HH + j] = hnew;     // capture at len-1
                }
            }
        }
        __syncthreads();   // one barrier per tick orders all handoffs
    }
}

__global__ __launch_bounds__(256)
void fc_head(const float* __restrict__ last,
             const float* __restrict__ fcW,   // [C][H]
             const float* __restrict__ fcb,   // [C]
             float* __restrict__ out)         // [B][C]
{
    int b = blockIdx.x * blockDim.x + threadIdx.x;
    if (b >= BB) return;
    float lg[CC];
#pragma unroll
    for (int c = 0; c < CC; c++) lg[c] = fcb[c];
#pragma unroll
    for (int j = 0; j < HH; j++) {
        float h = last[(size_t)b * HH + j];
#pragma unroll
        for (int c = 0; c < CC; c++) lg[c] = fmaf(fcW[c * HH + j], h, lg[c]);
    }
    float m = lg[0];
#pragma unroll
    for (int c = 1; c < CC; c++) m = fmaxf(m, lg[c]);
    float s = 0.0f;
#pragma unroll
    for (int c = 0; c < CC; c++) s += __expf(lg[c] - m);
    float lse = m + logf(s);
#pragma unroll
    for (int c = 0; c < CC; c++) out[(size_t)b * CC + c] = lg[c] - lse;
}

extern "C" void kernel_launch(void* const* d_in, const int* in_sizes, int n_in,
                              void* d_out, int out_size, void* d_ws, size_t ws_size,
                              hipStream_t stream)
{
    const float* x    = (const float*)d_in[0];
    const float* Wih0 = (const float*)d_in[1];
    const float* Whh0 = (const float*)d_in[2];
    const float* bih0 = (const float*)d_in[3];
    const float* bhh0 = (const float*)d_in[4];
    const float* Wih  = (const float*)d_in[5];
    const float* Whh  = (const float*)d_in[6];
    const float* bih  = (const float*)d_in[7];
    const float* bhh  = (const float*)d_in[8];
    const float* fcW  = (const float*)d_in[9];
    const float* fcb  = (const float*)d_in[10];
    const int*   lens = (const int*)d_in[11];
    float* out = (float*)d_out;

    float* last = (float*)d_ws;   // [B][32] = 512 KB

    gru_fused<<<dim3(BB), dim3(NTH), 0, stream>>>(
        x, Wih0, Whh0, bih0, bhh0, Wih, Whh, bih, bhh, lens, last);

    fc_head<<<dim3(BB / 256), dim3(256), 0, stream>>>(last, fcW, fcb, out);
}

// Round 4
// 1737.177 us; speedup vs baseline: 6.2837x; 4.2677x over previous
//
#include <hip/hip_runtime.h>
#include <math.h>

#define TT 512
#define BB 4096
#define IN_DIM 12
#define HH 32
#define LL 10
#define CC 4
#define NTH (LL * 64)   // 640 threads = 10 waves, one per layer

typedef _Float16 half8 __attribute__((ext_vector_type(8)));
typedef _Float16 half4 __attribute__((ext_vector_type(4)));
typedef float f32x4 __attribute__((ext_vector_type(4)));

// f16-element offsets inside the shared lds16 arena.
// Layout of each 512-f16 panel: [4 kquad][16 b][8 f16] — B-fragment order,
// lane (b=lane&15, quad=lane>>4) reads its 8 k-values at lane*8 (lane-linear).
#define HS_HI 0                       // hself hi: [10 layer][2 buf][512]
#define HS_LO (LL * 1024)             // hself lo
#define XS_HI (2 * LL * 1024)         // x stage hi: [2 buf][512]
#define XS_LO (2 * LL * 1024 + 1024)  // x stage lo
#define LDS16_TOT (2 * LL * 1024 + 2048)  // 22528 f16 = 45 KB

__device__ __forceinline__ float sigmoidf_(float x) {
    return 1.0f / (1.0f + __expf(-x));
}
// branch-free tanh: 1 - 2/(e^{2x}+1)
__device__ __forceinline__ float tanhfast_(float x) {
    float e = __expf(2.0f * x);
    return 1.0f - 2.0f / (e + 1.0f);
}

#define MFMA_(A, B, C) C = __builtin_amdgcn_mfma_f32_16x16x32_f16(A, B, C, 0, 0, 0)

// Fused 10-layer GRU, temporal pipeline + MFMA cells.
// Block = 10 waves = 16 batch elements; wave w runs layer w at t = tick - w.
// Gates[96 rows x 16 b] = 8 MFMA C-tiles (R0,R1,Z0,Z1,IN0,IN1,HN0,HN1),
// K=64 split in 2 chunks (input | own h). fp32 weights/activations are split
// as f16 hi+lo; 3-term MFMA (Whi*Xhi + Whi*Xlo + Wlo*Xhi) keeps ~2^-22 error.
// A-frag: A[m=lane&15][k=quad*8+idx]; B-frag: B[k=quad*8+idx][n=lane&15];
// C/D: col=lane&15, row=quad*4+reg  (per verified gfx950 layouts).
__global__ __launch_bounds__(NTH, 3)
void gru_fused_mfma(const float* __restrict__ x,      // [T][B][12]
                    const float* __restrict__ Wih0,   // [96][12]
                    const float* __restrict__ Whh0,   // [96][32]
                    const float* __restrict__ bih0,   // [96]
                    const float* __restrict__ bhh0,   // [96]
                    const float* __restrict__ Wih,    // [9][96][32]
                    const float* __restrict__ Whh,    // [9][96][32]
                    const float* __restrict__ bih,    // [9][96]
                    const float* __restrict__ bhh,    // [9][96]
                    const int*   __restrict__ lengths,
                    float*       __restrict__ last)   // [B][32]
{
    __shared__ __align__(16) _Float16 lds16[LDS16_TOT];
    __shared__ __align__(16) float biasl[LL * 4 * HH];  // [w][{R,Z,IN,HN}][32]

    const int tid  = threadIdx.x;
    const int w    = tid >> 6;      // layer
    const int lane = tid & 63;
    const int bi16 = lane & 15;     // batch col within group
    const int quad = lane >> 4;
    const int bg   = blockIdx.x;    // batch group (16 elems)

    // ---- zero the f16 arena (h0 = 0 and x-stage padding) ----
    {
        float4 z4 = make_float4(0.f, 0.f, 0.f, 0.f);
        float4* p = (float4*)lds16;
        for (int i = tid; i < LDS16_TOT / 8; i += NTH) p[i] = z4;
    }
    __syncthreads();

    // ---- per-wave weight pointers ----
    const float *Wi, *Wh, *bivec, *bhvec;
    int wistride;
    if (w == 0) { Wi = Wih0; Wh = Whh0; bivec = bih0; bhvec = bhh0; wistride = IN_DIM; }
    else {
        Wi = Wih + (size_t)(w - 1) * 96 * HH;
        Wh = Whh + (size_t)(w - 1) * 96 * HH;
        bivec = bih + (size_t)(w - 1) * 96;
        bhvec = bhh + (size_t)(w - 1) * 96;
        wistride = HH;
    }

    // ---- stationary A-fragments (hi/lo) in VGPRs: 24 frags = 96 regs ----
    // frag f: rows frow[f]..+15, chunk fchk[f] (0=input side Wi, 1=h side Wh)
    // tiles: 0,1=R0(f0,f1),  2,3=R1, 4,5=Z0, 6,7=Z1, 8=IN0,9=IN1(c0), 10=HN0,11=HN1(c1)
    const int frow[12] = {0, 0, 16, 16, 32, 32, 48, 48, 64, 80, 64, 80};
    const int fchk[12] = {0, 1, 0, 1, 0, 1, 0, 1, 0, 0, 1, 1};
    half8 Whi[12], Wlo[12];
#pragma unroll
    for (int f = 0; f < 12; f++) {
        int row = frow[f] + bi16;
        const float* src; int kin;
        if (fchk[f] == 0) { src = Wi + (size_t)row * wistride; kin = wistride; }
        else              { src = Wh + (size_t)row * HH;       kin = HH; }
#pragma unroll
        for (int kk = 0; kk < 8; kk++) {
            int k = quad * 8 + kk;
            float v = (k < kin) ? src[k] : 0.0f;
            _Float16 h = (_Float16)v;
            Whi[f][kk] = h;
            Wlo[f][kk] = (_Float16)(v - (float)h);
        }
    }

    // ---- biases into LDS (read per tick directly into the accumulators) ----
    if (lane < HH) {
        int j = lane;
        biasl[(w * 4 + 0) * HH + j] = bivec[j]          + bhvec[j];          // r
        biasl[(w * 4 + 1) * HH + j] = bivec[HH + j]     + bhvec[HH + j];     // z
        biasl[(w * 4 + 2) * HH + j] = bivec[2 * HH + j];                     // i_n
        biasl[(w * 4 + 3) * HH + j] = bhvec[2 * HH + j];                     // h_n
    }

    // ---- stage x[0] into xstage buf0 (wave 0, lanes 0-47, float4 each) ----
    if (w == 0 && lane < 48) {
        int bb = lane / 3, kg = lane - bb * 3;    // b row, k-group (4 floats)
        float4 xl = *(const float4*)(x + (size_t)bg * 192 + lane * 4);
        float xa[4] = {xl.x, xl.y, xl.z, xl.w};
        half4 h4, l4;
#pragma unroll
        for (int i = 0; i < 4; i++) {
            _Float16 hh16 = (_Float16)xa[i];
            h4[i] = hh16; l4[i] = (_Float16)(xa[i] - (float)hh16);
        }
        int q = (kg == 2) ? 1 : 0, off = (kg == 1) ? 4 : 0;
        int idx = q * 128 + bb * 8 + off;
        *(half4*)(lds16 + XS_HI + idx) = h4;
        *(half4*)(lds16 + XS_LO + idx) = l4;
    }

    int mylen = 0;
    if (w == LL - 1) {
        int len = lengths[bg * 16 + bi16];
        mylen = (len < 1) ? 1 : len;
    }

    const int laneoff    = lane * 8;
    const int inbase_hi  = (w == 0) ? XS_HI : (HS_HI + (w - 1) * 1024);
    const int inbase_lo  = (w == 0) ? XS_LO : (HS_LO + (w - 1) * 1024);
    const int ownbase_hi = HS_HI + w * 1024;
    const int ownbase_lo = HS_LO + w * 1024;

    float hprev[8] = {0, 0, 0, 0, 0, 0, 0, 0};   // C-layout h (2 jt-tiles x 4 rows)

    __syncthreads();

    for (int tick = 0; tick < TT + LL - 1; ++tick) {
        int t = tick - w;
        if (0 <= t && t < TT) {
            int p = t & 1;
            // B-frags: input chunk (x or previous layer's h) and own h
            half8 bxh = *(const half8*)(lds16 + inbase_hi  + p * 512 + laneoff);
            half8 bxl = *(const half8*)(lds16 + inbase_lo  + p * 512 + laneoff);
            half8 bhh = *(const half8*)(lds16 + ownbase_hi + (p ^ 1) * 512 + laneoff);
            half8 bhl = *(const half8*)(lds16 + ownbase_lo + (p ^ 1) * 512 + laneoff);

            // wave 0: prefetch x[t+1] (global)
            float xa[4];
            bool doload = (w == 0) && (lane < 48) && (t + 1 < TT);
            if (doload) {
                float4 xl = *(const float4*)(x + (size_t)(t + 1) * BB * IN_DIM +
                                             (size_t)bg * 192 + lane * 4);
                xa[0] = xl.x; xa[1] = xl.y; xa[2] = xl.z; xa[3] = xl.w;
            }

            // accumulators init = bias (broadcast ds_read_b128 per tile)
            f32x4 acc[8];
#pragma unroll
            for (int ct = 0; ct < 8; ct++) {
                int g = ct >> 1, jt = ct & 1;
                acc[ct] = *(const f32x4*)(biasl + (w * 4 + g) * HH + jt * 16 + quad * 4);
            }

            // 36 MFMAs: r/z tiles use both chunks; i_n chunk0 only; h_n chunk1 only
#pragma unroll
            for (int ct = 0; ct < 4; ct++) {
                MFMA_(Whi[ct * 2 + 0], bxh, acc[ct]);
                MFMA_(Whi[ct * 2 + 1], bhh, acc[ct]);
                MFMA_(Whi[ct * 2 + 0], bxl, acc[ct]);
                MFMA_(Whi[ct * 2 + 1], bhl, acc[ct]);
                MFMA_(Wlo[ct * 2 + 0], bxh, acc[ct]);
                MFMA_(Wlo[ct * 2 + 1], bhh, acc[ct]);
            }
#pragma unroll
            for (int jt = 0; jt < 2; jt++) {
                MFMA_(Whi[8 + jt],  bxh, acc[4 + jt]);
                MFMA_(Whi[8 + jt],  bxl, acc[4 + jt]);
                MFMA_(Wlo[8 + jt],  bxh, acc[4 + jt]);
                MFMA_(Whi[10 + jt], bhh, acc[6 + jt]);
                MFMA_(Whi[10 + jt], bhl, acc[6 + jt]);
                MFMA_(Wlo[10 + jt], bhh, acc[6 + jt]);
            }

            // ---- epilogue: activations + h update + store h as f16 hi/lo ----
#pragma unroll
            for (int jt = 0; jt < 2; jt++) {
                f32x4 R = acc[0 + jt], Z = acc[2 + jt];
                f32x4 IN_ = acc[4 + jt], HN = acc[6 + jt];
                half4 h4, l4;
                float hv[4];
#pragma unroll
                for (int r = 0; r < 4; r++) {
                    float rv = sigmoidf_(R[r]);
                    float zv = sigmoidf_(Z[r]);
                    float nv = tanhfast_(fmaf(rv, HN[r], IN_[r]));
                    float h  = fmaf(zv, hprev[jt * 4 + r] - nv, nv);
                    hprev[jt * 4 + r] = h;
                    _Float16 hh16 = (_Float16)h;
                    h4[r] = hh16;
                    l4[r] = (_Float16)(h - (float)hh16);
                    hv[r] = h;
                }
                // C-layout (b=bi16, j=jt*16+quad*4+r) -> B-frag layout slot
                int c  = jt * 2 + (quad >> 1);
                int wi = c * 128 + bi16 * 8 + (quad & 1) * 4;
                *(half4*)(lds16 + ownbase_hi + p * 512 + wi) = h4;
                *(half4*)(lds16 + ownbase_lo + p * 512 + wi) = l4;
                if (w == LL - 1 && t == mylen - 1) {
                    float4 o = make_float4(hv[0], hv[1], hv[2], hv[3]);
                    *(float4*)(last + (size_t)(bg * 16 + bi16) * HH + jt * 16 + quad * 4) = o;
                }
            }

            // wave 0: convert + store prefetched x into buf p^1
            if (doload) {
                int bb = lane / 3, kg = lane - (lane / 3) * 3;
                half4 h4, l4;
#pragma unroll
                for (int i = 0; i < 4; i++) {
                    _Float16 hh16 = (_Float16)xa[i];
                    h4[i] = hh16; l4[i] = (_Float16)(xa[i] - (float)hh16);
                }
                int q = (kg == 2) ? 1 : 0, off = (kg == 1) ? 4 : 0;
                int idx = q * 128 + bb * 8 + off;
                *(half4*)(lds16 + XS_HI + (p ^ 1) * 512 + idx) = h4;
                *(half4*)(lds16 + XS_LO + (p ^ 1) * 512 + idx) = l4;
            }
        }
        __syncthreads();   // one barrier per tick orders all handoffs
    }
}

__global__ __launch_bounds__(256)
void fc_head(const float* __restrict__ last,
             const float* __restrict__ fcW,   // [C][H]
             const float* __restrict__ fcb,   // [C]
             float* __restrict__ out)         // [B][C]
{
    int b = blockIdx.x * blockDim.x + threadIdx.x;
    if (b >= BB) return;
    float lg[CC];
#pragma unroll
    for (int c = 0; c < CC; c++) lg[c] = fcb[c];
#pragma unroll
    for (int j = 0; j < HH; j++) {
        float h = last[(size_t)b * HH + j];
#pragma unroll
        for (int c = 0; c < CC; c++) lg[c] = fmaf(fcW[c * HH + j], h, lg[c]);
    }
    float m = lg[0];
#pragma unroll
    for (int c = 1; c < CC; c++) m = fmaxf(m, lg[c]);
    float s = 0.0f;
#pragma unroll
    for (int c = 0; c < CC; c++) s += __expf(lg[c] - m);
    float lse = m + logf(s);
#pragma unroll
    for (int c = 0; c < CC; c++) out[(size_t)b * CC + c] = lg[c] - lse;
}

extern "C" void kernel_launch(void* const* d_in, const int* in_sizes, int n_in,
                              void* d_out, int out_size, void* d_ws, size_t ws_size,
                              hipStream_t stream)
{
    const float* x    = (const float*)d_in[0];
    const float* Wih0 = (const float*)d_in[1];
    const float* Whh0 = (const float*)d_in[2];
    const float* bih0 = (const float*)d_in[3];
    const float* bhh0 = (const float*)d_in[4];
    const float* Wih  = (const float*)d_in[5];
    const float* Whh  = (const float*)d_in[6];
    const float* bih  = (const float*)d_in[7];
    const float* bhh  = (const float*)d_in[8];
    const float* fcW  = (const float*)d_in[9];
    const float* fcb  = (const float*)d_in[10];
    const int*   lens = (const int*)d_in[11];
    float* out = (float*)d_out;

    float* last = (float*)d_ws;   // [B][32] = 512 KB

    gru_fused_mfma<<<dim3(BB / 16), dim3(NTH), 0, stream>>>(
        x, Wih0, Whh0, bih0, bhh0, Wih, Whh, bih, bhh, lens, last);

    fc_head<<<dim3(BB / 256), dim3(256), 0, stream>>>(last, fcW, fcb, out);
}

// Round 5
// 1620.962 us; speedup vs baseline: 6.7342x; 1.0717x over previous
//
#include <hip/hip_runtime.h>
#include <math.h>

#define TT 512
#define BB 4096
#define IN_DIM 12
#define HH 32
#define LL 10
#define CC 4
#define NTH (LL * 64)        // 640 threads = 10 waves, one per layer
#define SS (TT / 2 + LL - 1) // 265 super-ticks (2 timesteps each)

typedef _Float16 half8 __attribute__((ext_vector_type(8)));
typedef _Float16 half4 __attribute__((ext_vector_type(4)));
typedef float f32x4 __attribute__((ext_vector_type(4)));

#define LOG2E 1.44269504088896340736f

// f16-unit offsets in the LDS arena (total 31744 f16 = 62 KB static):
//  H_HI: per-layer h hi panels, 4 slots (mod-4 of t) — cross-wave handoff
//  H_LO: per-layer h lo panels, 2 slots — wave-internal (own recurrence only)
//  X_HI: wave-0 x panels, 2 slots — wave-internal
#define H_HI 0
#define H_LO (LL * 4 * 512)              // 20480
#define X_HI (H_LO + LL * 2 * 512)      // 30720
#define LDS16_TOT (X_HI + 2 * 512)      // 31744

#define MFMA_(A, B, C) C = __builtin_amdgcn_mfma_f32_16x16x32_f16(A, B, C, 0, 0, 0)

// Fused 10-layer GRU: temporal pipeline across 10 waves, MFMA cells,
// 2 timesteps per barrier. Weights pre-scaled by -log2e (r,z rows) and
// 2*log2e (n rows) so activations need only v_exp/v_rcp.
// Within-layer recurrence: h kept as f16 hi+lo (exact to ~2^-22).
// Inter-layer handoff: f16 only (non-recurrent quantization noise).
__global__ __launch_bounds__(NTH, 2)
void gru_fused_mfma(const float* __restrict__ x,      // [T][B][12]
                    const float* __restrict__ Wih0,   // [96][12]
                    const float* __restrict__ Whh0,   // [96][32]
                    const float* __restrict__ bih0,   // [96]
                    const float* __restrict__ bhh0,   // [96]
                    const float* __restrict__ Wih,    // [9][96][32]
                    const float* __restrict__ Whh,    // [9][96][32]
                    const float* __restrict__ bih,    // [9][96]
                    const float* __restrict__ bhh,    // [9][96]
                    const int*   __restrict__ lengths,
                    float*       __restrict__ last)   // [B][32]
{
    __shared__ __align__(16) _Float16 lds16[LDS16_TOT];

    const int tid  = threadIdx.x;
    const int w    = tid >> 6;      // layer
    const int lane = tid & 63;
    const int bi16 = lane & 15;     // batch col within group
    const int quad = lane >> 4;
    const int bg   = blockIdx.x;    // batch group (16 elems)

    // ---- zero the arena (h0 = 0, zero-padding) ----
    {
        float4 z4 = make_float4(0.f, 0.f, 0.f, 0.f);
        float4* p = (float4*)lds16;
        for (int i = tid; i < LDS16_TOT / 8; i += NTH) p[i] = z4;
    }
    __syncthreads();

    // ---- per-wave weight pointers ----
    const float *Wi, *Wh, *bivec, *bhvec;
    int wistride;
    if (w == 0) { Wi = Wih0; Wh = Whh0; bivec = bih0; bhvec = bhh0; wistride = IN_DIM; }
    else {
        Wi = Wih + (size_t)(w - 1) * 96 * HH;
        Wh = Whh + (size_t)(w - 1) * 96 * HH;
        bivec = bih + (size_t)(w - 1) * 96;
        bhvec = bhh + (size_t)(w - 1) * 96;
        wistride = HH;
    }

    // ---- stationary A-fragments (hi/lo, pre-scaled) ----
    // f0..f7: r/z tiles, pairs (chunk0=Wi, chunk1=Wh); f8,f9: IN (Wi); f10,f11: HN (Wh)
    const int frow[12] = {0, 0, 16, 16, 32, 32, 48, 48, 64, 80, 64, 80};
    const int fchk[12] = {0, 1, 0, 1, 0, 1, 0, 1, 0, 0, 1, 1};
    half8 Whi[12], Wlo[12];
#pragma unroll
    for (int f = 0; f < 12; f++) {
        const float sc = (f < 8) ? -LOG2E : 2.0f * LOG2E;
        int row = frow[f] + bi16;
        const float* src; int kin;
        if (fchk[f] == 0) { src = Wi + (size_t)row * wistride; kin = wistride; }
        else              { src = Wh + (size_t)row * HH;       kin = HH; }
#pragma unroll
        for (int kk = 0; kk < 8; kk++) {
            int k = quad * 8 + kk;
            float v = (k < kin) ? src[k] * sc : 0.0f;
            _Float16 h = (_Float16)v;
            Whi[f][kk] = h;
            Wlo[f][kk] = (_Float16)(v - (float)h);
        }
    }

    // ---- biases in registers (pre-scaled, per C-tile f32x4) ----
    f32x4 biasreg[8];
#pragma unroll
    for (int ct = 0; ct < 8; ct++) {
        int g = ct >> 1, jt = ct & 1;
#pragma unroll
        for (int r = 0; r < 4; r++) {
            int j = jt * 16 + quad * 4 + r;
            float v;
            if      (g == 0) v = -(bivec[j]      + bhvec[j])      * LOG2E;
            else if (g == 1) v = -(bivec[32 + j] + bhvec[32 + j]) * LOG2E;
            else if (g == 2) v = bivec[64 + j] * (2.0f * LOG2E);
            else             v = bhvec[64 + j] * (2.0f * LOG2E);
            biasreg[ct][r] = v;
        }
    }

    int capT = -1;   // last-layer capture timestep per lane
    if (w == LL - 1) {
        int len = lengths[bg * 16 + bi16];
        capT = ((len < 1) ? 1 : len) - 1;
    }

    const int laneoff = lane * 8;
    const int inbase  = (w == 0) ? X_HI : (H_HI + (w - 1) * 2048);
    const int inmask  = (w == 0) ? 1 : 3;
    const int ownhi   = H_HI + w * 2048;
    const int ownlo   = H_LO + w * 1024;
    const int wibase  = (quad >> 1) * 128 + bi16 * 8 + (quad & 1) * 4;

    // x staging constants (wave 0, lanes 0-47)
    const int xbb = lane / 3, xkg = lane - xbb * 3;
    const int xq   = (xkg == 2) ? 1 : 0;
    const int xoff = (xkg == 1) ? 4 : 0;
    const int xidx = xq * 128 + xbb * 8 + xoff;
    const bool xlane = (w == 0) && (lane < 48);

    auto stage_x = [&](const float4& xl, int t) {
        half4 h4;
        h4[0] = (_Float16)xl.x; h4[1] = (_Float16)xl.y;
        h4[2] = (_Float16)xl.z; h4[3] = (_Float16)xl.w;
        *(half4*)(lds16 + X_HI + ((t & 1) << 9) + xidx) = h4;
    };

    // stage x[0], x[1]
    if (xlane) {
        float4 x0 = *(const float4*)(x + (size_t)bg * 192 + lane * 4);
        float4 x1 = *(const float4*)(x + (size_t)BB * IN_DIM + (size_t)bg * 192 + lane * 4);
        stage_x(x0, 0);
        stage_x(x1, 1);
    }

    float hprev[8] = {0, 0, 0, 0, 0, 0, 0, 0};
    __syncthreads();

    auto substep = [&](int t) {
        // B-fragments: input (f16 only) + own h (hi+lo)
        half8 bxh = *(const half8*)(lds16 + inbase + ((t & inmask) << 9) + laneoff);
        half8 bhh = *(const half8*)(lds16 + ownhi + (((t + 3) & 3) << 9) + laneoff);
        half8 bhl = *(const half8*)(lds16 + ownlo + (((t + 1) & 1) << 9) + laneoff);

        f32x4 acc[8];
#pragma unroll
        for (int ct = 0; ct < 8; ct++) acc[ct] = biasreg[ct];

        // 30 MFMAs: r/z tiles 5 each; IN 2 each; HN 3 each
#pragma unroll
        for (int ct = 0; ct < 4; ct++) {
            MFMA_(Whi[ct * 2 + 0], bxh, acc[ct]);
            MFMA_(Whi[ct * 2 + 1], bhh, acc[ct]);
            MFMA_(Wlo[ct * 2 + 0], bxh, acc[ct]);
            MFMA_(Whi[ct * 2 + 1], bhl, acc[ct]);
            MFMA_(Wlo[ct * 2 + 1], bhh, acc[ct]);
        }
#pragma unroll
        for (int jt = 0; jt < 2; jt++) {
            MFMA_(Whi[8 + jt],  bxh, acc[4 + jt]);
            MFMA_(Wlo[8 + jt],  bxh, acc[4 + jt]);
            MFMA_(Whi[10 + jt], bhh, acc[6 + jt]);
            MFMA_(Whi[10 + jt], bhl, acc[6 + jt]);
            MFMA_(Wlo[10 + jt], bhh, acc[6 + jt]);
        }

        // epilogue: r = rcp(1+exp2(accR)), z likewise,
        // n = 1 - 2*rcp(exp2(IN + r*HN)+1)  (scales pre-folded into W/b)
#pragma unroll
        for (int jt = 0; jt < 2; jt++) {
            f32x4 R = acc[0 + jt], Z = acc[2 + jt];
            f32x4 IN_ = acc[4 + jt], HN = acc[6 + jt];
            half4 h4, l4;
            float hv[4];
#pragma unroll
            for (int r = 0; r < 4; r++) {
                float rv = __builtin_amdgcn_rcpf(1.0f + __builtin_amdgcn_exp2f(R[r]));
                float zv = __builtin_amdgcn_rcpf(1.0f + __builtin_amdgcn_exp2f(Z[r]));
                float ea = __builtin_amdgcn_exp2f(fmaf(rv, HN[r], IN_[r]));
                float nv = fmaf(-2.0f, __builtin_amdgcn_rcpf(ea + 1.0f), 1.0f);
                float h  = fmaf(zv, hprev[jt * 4 + r] - nv, nv);
                hprev[jt * 4 + r] = h;
                _Float16 hh16 = (_Float16)h;
                h4[r] = hh16;
                l4[r] = (_Float16)(h - (float)hh16);
                hv[r] = h;
            }
            int wi = jt * 256 + wibase;
            *(half4*)(lds16 + ownhi + ((t & 3) << 9) + wi) = h4;
            *(half4*)(lds16 + ownlo + ((t & 1) << 9) + wi) = l4;
            if (w == LL - 1 && t == capT) {
                float4 o = make_float4(hv[0], hv[1], hv[2], hv[3]);
                *(float4*)(last + (size_t)(bg * 16 + bi16) * HH + jt * 16 + quad * 4) = o;
            }
        }
    };

    for (int s = 0; s < SS; ++s) {
        const bool active = (unsigned)(s - w) < (unsigned)(TT / 2);
        const int t0 = 2 * (s - w);

        // wave 0: prefetch x[t0+2], x[t0+3] early (regs), stage late
        float4 xa0, xa1;
        bool dl0 = false, dl1 = false;
        if (xlane && active) {
            if (t0 + 2 < TT) {
                xa0 = *(const float4*)(x + (size_t)(t0 + 2) * BB * IN_DIM +
                                       (size_t)bg * 192 + lane * 4);
                dl0 = true;
            }
            if (t0 + 3 < TT) {
                xa1 = *(const float4*)(x + (size_t)(t0 + 3) * BB * IN_DIM +
                                       (size_t)bg * 192 + lane * 4);
                dl1 = true;
            }
        }

        if (active) {
            substep(t0);
            substep(t0 + 1);
        }
        if (dl0) stage_x(xa0, t0 + 2);
        if (dl1) stage_x(xa1, t0 + 3);

        __syncthreads();   // orders the cross-wave hi-panel handoff
    }
}

__global__ __launch_bounds__(256)
void fc_head(const float* __restrict__ last,
             const float* __restrict__ fcW,   // [C][H]
             const float* __restrict__ fcb,   // [C]
             float* __restrict__ out)         // [B][C]
{
    int b = blockIdx.x * blockDim.x + threadIdx.x;
    if (b >= BB) return;
    float lg[CC];
#pragma unroll
    for (int c = 0; c < CC; c++) lg[c] = fcb[c];
#pragma unroll
    for (int j = 0; j < HH; j++) {
        float h = last[(size_t)b * HH + j];
#pragma unroll
        for (int c = 0; c < CC; c++) lg[c] = fmaf(fcW[c * HH + j], h, lg[c]);
    }
    float m = lg[0];
#pragma unroll
    for (int c = 1; c < CC; c++) m = fmaxf(m, lg[c]);
    float s = 0.0f;
#pragma unroll
    for (int c = 0; c < CC; c++) s += __expf(lg[c] - m);
    float lse = m + logf(s);
#pragma unroll
    for (int c = 0; c < CC; c++) out[(size_t)b * CC + c] = lg[c] - lse;
}

extern "C" void kernel_launch(void* const* d_in, const int* in_sizes, int n_in,
                              void* d_out, int out_size, void* d_ws, size_t ws_size,
                              hipStream_t stream)
{
    const float* x    = (const float*)d_in[0];
    const float* Wih0 = (const float*)d_in[1];
    const float* Whh0 = (const float*)d_in[2];
    const float* bih0 = (const float*)d_in[3];
    const float* bhh0 = (const float*)d_in[4];
    const float* Wih  = (const float*)d_in[5];
    const float* Whh  = (const float*)d_in[6];
    const float* bih  = (const float*)d_in[7];
    const float* bhh  = (const float*)d_in[8];
    const float* fcW  = (const float*)d_in[9];
    const float* fcb  = (const float*)d_in[10];
    const int*   lens = (const int*)d_in[11];
    float* out = (float*)d_out;

    float* last = (float*)d_ws;   // [B][32] = 512 KB

    gru_fused_mfma<<<dim3(BB / 16), dim3(NTH), 0, stream>>>(
        x, Wih0, Whh0, bih0, bhh0, Wih, Whh, bih, bhh, lens, last);

    fc_head<<<dim3(BB / 256), dim3(256), 0, stream>>>(last, fcW, fcb, out);
}

// Round 6
// 980.347 us; speedup vs baseline: 11.1347x; 1.6535x over previous
//
#include <hip/hip_runtime.h>
#include <math.h>

#define TT 512
#define BB 4096
#define IN_DIM 12
#define HH 32
#define LL 10
#define CC 4
#define NTH (LL * 64)        // 640 threads = 10 waves, one per layer
#define SS (TT / 2 + LL - 1) // 265 super-ticks (2 timesteps each)

typedef _Float16 half8 __attribute__((ext_vector_type(8)));
typedef _Float16 half4 __attribute__((ext_vector_type(4)));
typedef float f32x4 __attribute__((ext_vector_type(4)));

#define LOG2E 1.44269504088896340736f

// f16-unit offsets in the LDS arena (total 31744 f16 = 62 KB static):
//  H_HI: per-layer h hi panels, 4 slots (mod-4 of t) — cross-wave handoff
//  H_LO: per-layer h lo panels, 2 slots — wave-internal (own recurrence only)
//  X_HI: wave-0 x panels, 2 slots — wave-internal
#define H_HI 0
#define H_LO (LL * 4 * 512)             // 20480
#define X_HI (H_LO + LL * 2 * 512)      // 30720
#define LDS16_TOT (X_HI + 2 * 512)      // 31744

#define MFMA_(A, B, C) C = __builtin_amdgcn_mfma_f32_16x16x32_f16(A, B, C, 0, 0, 0)

// Fused 10-layer GRU: temporal pipeline across 10 waves, MFMA cells,
// 2 timesteps per barrier. Weights pre-scaled by -log2e (r,z rows) and
// 2*log2e (n rows) so activations need only v_exp2/v_rcp.
// Recurrent h-path: full f16 hi+lo 3-term split (exact to ~2^-22).
// Input path (x / inter-layer handoff): f16 hi-only, 1 MFMA term —
// non-recurrent quantization noise, saves 24 weight VGPRs + 6 MFMAs
// (de-spill: round 5's biasreg pushed allocation into per-tick scratch
// spills — 22 MB WRITE_SIZE — which serialized the recurrence).
__global__ __launch_bounds__(NTH, 2)
void gru_fused_mfma(const float* __restrict__ x,      // [T][B][12]
                    const float* __restrict__ Wih0,   // [96][12]
                    const float* __restrict__ Whh0,   // [96][32]
                    const float* __restrict__ bih0,   // [96]
                    const float* __restrict__ bhh0,   // [96]
                    const float* __restrict__ Wih,    // [9][96][32]
                    const float* __restrict__ Whh,    // [9][96][32]
                    const float* __restrict__ bih,    // [9][96]
                    const float* __restrict__ bhh,    // [9][96]
                    const int*   __restrict__ lengths,
                    float*       __restrict__ last)   // [B][32]
{
    __shared__ __align__(16) _Float16 lds16[LDS16_TOT];

    const int tid  = threadIdx.x;
    const int w    = tid >> 6;      // layer
    const int lane = tid & 63;
    const int bi16 = lane & 15;     // batch col within group
    const int quad = lane >> 4;
    const int bg   = blockIdx.x;    // batch group (16 elems)

    // ---- zero the arena (h0 = 0, zero-padding) ----
    {
        float4 z4 = make_float4(0.f, 0.f, 0.f, 0.f);
        float4* p = (float4*)lds16;
        for (int i = tid; i < LDS16_TOT / 8; i += NTH) p[i] = z4;
    }
    __syncthreads();

    // ---- per-wave weight pointers ----
    const float *Wi, *Wh, *bivec, *bhvec;
    int wistride;
    if (w == 0) { Wi = Wih0; Wh = Whh0; bivec = bih0; bhvec = bhh0; wistride = IN_DIM; }
    else {
        Wi = Wih + (size_t)(w - 1) * 96 * HH;
        Wh = Whh + (size_t)(w - 1) * 96 * HH;
        bivec = bih + (size_t)(w - 1) * 96;
        bhvec = bhh + (size_t)(w - 1) * 96;
        wistride = HH;
    }

    // ---- stationary A-fragments (pre-scaled) ----
    // f0..f7: r/z tiles, pairs (chunk0=Wi, chunk1=Wh); f8,f9: IN (Wi);
    // f10,f11: HN (Wh). Wlo kept only for the 6 h-side (Wh) frags:
    // f1->0, f3->1, f5->2, f7->3, f10->4, f11->5.
    const int frow[12] = {0, 0, 16, 16, 32, 32, 48, 48, 64, 80, 64, 80};
    const int fchk[12] = {0, 1, 0, 1, 0, 1, 0, 1, 0, 0, 1, 1};
    half8 Whi[12], Wlo[6];
#pragma unroll
    for (int f = 0; f < 12; f++) {
        const float sc = (f < 8) ? -LOG2E : 2.0f * LOG2E;
        int row = frow[f] + bi16;
        const float* src; int kin;
        if (fchk[f] == 0) { src = Wi + (size_t)row * wistride; kin = wistride; }
        else              { src = Wh + (size_t)row * HH;       kin = HH; }
        int wloidx = (f < 8) ? (f >> 1) : (f - 6);
#pragma unroll
        for (int kk = 0; kk < 8; kk++) {
            int k = quad * 8 + kk;
            float v = (k < kin) ? src[k] * sc : 0.0f;
            _Float16 h = (_Float16)v;
            Whi[f][kk] = h;
            if (fchk[f] == 1) Wlo[wloidx][kk] = (_Float16)(v - (float)h);
        }
    }

    // ---- biases in registers (pre-scaled, per C-tile f32x4) ----
    f32x4 biasreg[8];
#pragma unroll
    for (int ct = 0; ct < 8; ct++) {
        int g = ct >> 1, jt = ct & 1;
#pragma unroll
        for (int r = 0; r < 4; r++) {
            int j = jt * 16 + quad * 4 + r;
            float v;
            if      (g == 0) v = -(bivec[j]      + bhvec[j])      * LOG2E;
            else if (g == 1) v = -(bivec[32 + j] + bhvec[32 + j]) * LOG2E;
            else if (g == 2) v = bivec[64 + j] * (2.0f * LOG2E);
            else             v = bhvec[64 + j] * (2.0f * LOG2E);
            biasreg[ct][r] = v;
        }
    }

    int capT = -1;   // last-layer capture timestep per lane
    if (w == LL - 1) {
        int len = lengths[bg * 16 + bi16];
        capT = ((len < 1) ? 1 : len) - 1;
    }

    const int laneoff = lane * 8;
    const int inbase  = (w == 0) ? X_HI : (H_HI + (w - 1) * 2048);
    const int inmask  = (w == 0) ? 1 : 3;
    const int ownhi   = H_HI + w * 2048;
    const int ownlo   = H_LO + w * 1024;
    const int wibase  = (quad >> 1) * 128 + bi16 * 8 + (quad & 1) * 4;

    // x staging constants (wave 0, lanes 0-47)
    const int xbb = lane / 3, xkg = lane - xbb * 3;
    const int xq   = (xkg == 2) ? 1 : 0;
    const int xoff = (xkg == 1) ? 4 : 0;
    const int xidx = xq * 128 + xbb * 8 + xoff;
    const bool xlane = (w == 0) && (lane < 48);

    auto stage_x = [&](const float4& xl, int t) {
        half4 h4;
        h4[0] = (_Float16)xl.x; h4[1] = (_Float16)xl.y;
        h4[2] = (_Float16)xl.z; h4[3] = (_Float16)xl.w;
        *(half4*)(lds16 + X_HI + ((t & 1) << 9) + xidx) = h4;
    };

    // stage x[0], x[1]
    if (xlane) {
        float4 x0 = *(const float4*)(x + (size_t)bg * 192 + lane * 4);
        float4 x1 = *(const float4*)(x + (size_t)BB * IN_DIM + (size_t)bg * 192 + lane * 4);
        stage_x(x0, 0);
        stage_x(x1, 1);
    }

    float hprev[8] = {0, 0, 0, 0, 0, 0, 0, 0};
    __syncthreads();

    auto substep = [&](int t) {
        // B-fragments: input (f16 hi only) + own h (hi+lo)
        half8 bxh = *(const half8*)(lds16 + inbase + ((t & inmask) << 9) + laneoff);
        half8 bhh = *(const half8*)(lds16 + ownhi + (((t + 3) & 3) << 9) + laneoff);
        half8 bhl = *(const half8*)(lds16 + ownlo + (((t + 1) & 1) << 9) + laneoff);

        f32x4 acc[8];
#pragma unroll
        for (int ct = 0; ct < 8; ct++) acc[ct] = biasreg[ct];

        // 24 MFMAs: r/z tiles 4 each; IN 1 each; HN 3 each
#pragma unroll
        for (int ct = 0; ct < 4; ct++) {
            MFMA_(Whi[ct * 2 + 0], bxh, acc[ct]);
            MFMA_(Whi[ct * 2 + 1], bhh, acc[ct]);
            MFMA_(Whi[ct * 2 + 1], bhl, acc[ct]);
            MFMA_(Wlo[ct],         bhh, acc[ct]);
        }
#pragma unroll
        for (int jt = 0; jt < 2; jt++) {
            MFMA_(Whi[8 + jt],  bxh, acc[4 + jt]);
            MFMA_(Whi[10 + jt], bhh, acc[6 + jt]);
            MFMA_(Whi[10 + jt], bhl, acc[6 + jt]);
            MFMA_(Wlo[4 + jt],  bhh, acc[6 + jt]);
        }

        // epilogue: r = rcp(1+exp2(accR)), z likewise,
        // n = 1 - 2*rcp(exp2(IN + r*HN)+1)  (scales pre-folded into W/b)
#pragma unroll
        for (int jt = 0; jt < 2; jt++) {
            f32x4 R = acc[0 + jt], Z = acc[2 + jt];
            f32x4 IN_ = acc[4 + jt], HN = acc[6 + jt];
            half4 h4, l4;
            float hv[4];
#pragma unroll
            for (int r = 0; r < 4; r++) {
                float rv = __builtin_amdgcn_rcpf(1.0f + __builtin_amdgcn_exp2f(R[r]));
                float zv = __builtin_amdgcn_rcpf(1.0f + __builtin_amdgcn_exp2f(Z[r]));
                float ea = __builtin_amdgcn_exp2f(fmaf(rv, HN[r], IN_[r]));
                float nv = fmaf(-2.0f, __builtin_amdgcn_rcpf(ea + 1.0f), 1.0f);
                float h  = fmaf(zv, hprev[jt * 4 + r] - nv, nv);
                hprev[jt * 4 + r] = h;
                _Float16 hh16 = (_Float16)h;
                h4[r] = hh16;
                l4[r] = (_Float16)(h - (float)hh16);
                hv[r] = h;
            }
            int wi = jt * 256 + wibase;
            *(half4*)(lds16 + ownhi + ((t & 3) << 9) + wi) = h4;
            *(half4*)(lds16 + ownlo + ((t & 1) << 9) + wi) = l4;
            if (w == LL - 1 && t == capT) {
                float4 o = make_float4(hv[0], hv[1], hv[2], hv[3]);
                *(float4*)(last + (size_t)(bg * 16 + bi16) * HH + jt * 16 + quad * 4) = o;
            }
        }
    };

    for (int s = 0; s < SS; ++s) {
        const bool active = (unsigned)(s - w) < (unsigned)(TT / 2);
        const int t0 = 2 * (s - w);

        // wave 0: prefetch x[t0+2], x[t0+3] early (regs), stage late
        float4 xa0, xa1;
        bool dl0 = false, dl1 = false;
        if (xlane && active) {
            if (t0 + 2 < TT) {
                xa0 = *(const float4*)(x + (size_t)(t0 + 2) * BB * IN_DIM +
                                       (size_t)bg * 192 + lane * 4);
                dl0 = true;
            }
            if (t0 + 3 < TT) {
                xa1 = *(const float4*)(x + (size_t)(t0 + 3) * BB * IN_DIM +
                                       (size_t)bg * 192 + lane * 4);
                dl1 = true;
            }
        }

        if (active) {
            substep(t0);
            substep(t0 + 1);
        }
        if (dl0) stage_x(xa0, t0 + 2);
        if (dl1) stage_x(xa1, t0 + 3);

        __syncthreads();   // orders the cross-wave hi-panel handoff
    }
}

__global__ __launch_bounds__(256)
void fc_head(const float* __restrict__ last,
             const float* __restrict__ fcW,   // [C][H]
             const float* __restrict__ fcb,   // [C]
             float* __restrict__ out)         // [B][C]
{
    int b = blockIdx.x * blockDim.x + threadIdx.x;
    if (b >= BB) return;
    float lg[CC];
#pragma unroll
    for (int c = 0; c < CC; c++) lg[c] = fcb[c];
#pragma unroll
    for (int j = 0; j < HH; j++) {
        float h = last[(size_t)b * HH + j];
#pragma unroll
        for (int c = 0; c < CC; c++) lg[c] = fmaf(fcW[c * HH + j], h, lg[c]);
    }
    float m = lg[0];
#pragma unroll
    for (int c = 1; c < CC; c++) m = fmaxf(m, lg[c]);
    float s = 0.0f;
#pragma unroll
    for (int c = 0; c < CC; c++) s += __expf(lg[c] - m);
    float lse = m + logf(s);
#pragma unroll
    for (int c = 0; c < CC; c++) out[(size_t)b * CC + c] = lg[c] - lse;
}

extern "C" void kernel_launch(void* const* d_in, const int* in_sizes, int n_in,
                              void* d_out, int out_size, void* d_ws, size_t ws_size,
                              hipStream_t stream)
{
    const float* x    = (const float*)d_in[0];
    const float* Wih0 = (const float*)d_in[1];
    const float* Whh0 = (const float*)d_in[2];
    const float* bih0 = (const float*)d_in[3];
    const float* bhh0 = (const float*)d_in[4];
    const float* Wih  = (const float*)d_in[5];
    const float* Whh  = (const float*)d_in[6];
    const float* bih  = (const float*)d_in[7];
    const float* bhh  = (const float*)d_in[8];
    const float* fcW  = (const float*)d_in[9];
    const float* fcb  = (const float*)d_in[10];
    const int*   lens = (const int*)d_in[11];
    float* out = (float*)d_out;

    float* last = (float*)d_ws;   // [B][32] = 512 KB

    gru_fused_mfma<<<dim3(BB / 16), dim3(NTH), 0, stream>>>(
        x, Wih0, Whh0, bih0, bhh0, Wih, Whh, bih, bhh, lens, last);

    fc_head<<<dim3(BB / 256), dim3(256), 0, stream>>>(last, fcW, fcb, out);
}

// Round 7
// 958.580 us; speedup vs baseline: 11.3876x; 1.0227x over previous
//
#include <hip/hip_runtime.h>
#include <math.h>

#define TT 512
#define BB 4096
#define IN_DIM 12
#define HH 32
#define LL 10
#define CC 4
#define NTH (LL * 64)        // 640 threads = 10 waves, one per layer

typedef _Float16 half8 __attribute__((ext_vector_type(8)));
typedef _Float16 half4 __attribute__((ext_vector_type(4)));
typedef float f32x4 __attribute__((ext_vector_type(4)));

#define LOG2E 1.44269504088896340736f

// f16-unit offsets in the LDS arena (total 31744 f16 = 62 KB static):
//  H_HI: per-layer h hi panels, 4 slots (mod-4 of t) — cross-wave handoff
//  H_LO: per-layer h lo panels, 2 slots — wave-internal (own recurrence only)
//  X_HI: wave-0 x panels, 2 slots — wave-internal
#define H_HI 0
#define H_LO (LL * 4 * 512)             // 20480
#define X_HI (H_LO + LL * 2 * 512)      // 30720
#define LDS16_TOT (X_HI + 2 * 512)      // 31744

#define MFMA_(A, B, C) C = __builtin_amdgcn_mfma_f32_16x16x32_f16(A, B, C, 0, 0, 0)

// Fused 10-layer GRU: temporal pipeline across 10 waves, MFMA cells,
// SELF-TIMED producer-consumer sync (no __syncthreads in the main loop).
// Round 6 showed the per-super-tick barrier convoys all 10 waves into the
// same execution phase (LDS burst -> MFMA burst -> transcendental burst),
// serializing pipe usage: wall 8700 cyc/super-tick vs ~3500 of issue.
// Flags: flag[w] = last timestep published by wave w (release store after
// panel ds_writes drain); rflag[w] = last timestep consumed by wave w+1
// (back-pressure: writing t+1 overwrites slot of t-3, so need rflag >= t-3).
__global__ __launch_bounds__(NTH, 2)
void gru_fused_mfma(const float* __restrict__ x,      // [T][B][12]
                    const float* __restrict__ Wih0,   // [96][12]
                    const float* __restrict__ Whh0,   // [96][32]
                    const float* __restrict__ bih0,   // [96]
                    const float* __restrict__ bhh0,   // [96]
                    const float* __restrict__ Wih,    // [9][96][32]
                    const float* __restrict__ Whh,    // [9][96][32]
                    const float* __restrict__ bih,    // [9][96]
                    const float* __restrict__ bhh,    // [9][96]
                    const int*   __restrict__ lengths,
                    float*       __restrict__ last)   // [B][32]
{
    __shared__ __align__(16) _Float16 lds16[LDS16_TOT];
    __shared__ int flagS[LL];    // producer progress
    __shared__ int rflagS[LL];   // consumer progress (indexed by producer)

    const int tid  = threadIdx.x;
    const int w    = tid >> 6;      // layer
    const int lane = tid & 63;
    const int bi16 = lane & 15;     // batch col within group
    const int quad = lane >> 4;
    const int bg   = blockIdx.x;    // batch group (16 elems)

    // ---- zero the arena (h0 = 0, zero-padding) + init flags ----
    {
        float4 z4 = make_float4(0.f, 0.f, 0.f, 0.f);
        float4* p = (float4*)lds16;
        for (int i = tid; i < LDS16_TOT / 8; i += NTH) p[i] = z4;
    }
    if (lane == 0) { flagS[w] = -1; rflagS[w] = -1; }
    __syncthreads();

    // ---- per-wave weight pointers ----
    const float *Wi, *Wh, *bivec, *bhvec;
    int wistride;
    if (w == 0) { Wi = Wih0; Wh = Whh0; bivec = bih0; bhvec = bhh0; wistride = IN_DIM; }
    else {
        Wi = Wih + (size_t)(w - 1) * 96 * HH;
        Wh = Whh + (size_t)(w - 1) * 96 * HH;
        bivec = bih + (size_t)(w - 1) * 96;
        bhvec = bhh + (size_t)(w - 1) * 96;
        wistride = HH;
    }

    // ---- stationary A-fragments (pre-scaled) ----
    // f0..f7: r/z tiles, pairs (chunk0=Wi, chunk1=Wh); f8,f9: IN (Wi);
    // f10,f11: HN (Wh). Wlo kept only for the 6 h-side (Wh) frags.
    const int frow[12] = {0, 0, 16, 16, 32, 32, 48, 48, 64, 80, 64, 80};
    const int fchk[12] = {0, 1, 0, 1, 0, 1, 0, 1, 0, 0, 1, 1};
    half8 Whi[12], Wlo[6];
#pragma unroll
    for (int f = 0; f < 12; f++) {
        const float sc = (f < 8) ? -LOG2E : 2.0f * LOG2E;
        int row = frow[f] + bi16;
        const float* src; int kin;
        if (fchk[f] == 0) { src = Wi + (size_t)row * wistride; kin = wistride; }
        else              { src = Wh + (size_t)row * HH;       kin = HH; }
        int wloidx = (f < 8) ? (f >> 1) : (f - 6);
#pragma unroll
        for (int kk = 0; kk < 8; kk++) {
            int k = quad * 8 + kk;
            float v = (k < kin) ? src[k] * sc : 0.0f;
            _Float16 h = (_Float16)v;
            Whi[f][kk] = h;
            if (fchk[f] == 1) Wlo[wloidx][kk] = (_Float16)(v - (float)h);
        }
    }

    // ---- biases in registers (pre-scaled, per C-tile f32x4) ----
    f32x4 biasreg[8];
#pragma unroll
    for (int ct = 0; ct < 8; ct++) {
        int g = ct >> 1, jt = ct & 1;
#pragma unroll
        for (int r = 0; r < 4; r++) {
            int j = jt * 16 + quad * 4 + r;
            float v;
            if      (g == 0) v = -(bivec[j]      + bhvec[j])      * LOG2E;
            else if (g == 1) v = -(bivec[32 + j] + bhvec[32 + j]) * LOG2E;
            else if (g == 2) v = bivec[64 + j] * (2.0f * LOG2E);
            else             v = bhvec[64 + j] * (2.0f * LOG2E);
            biasreg[ct][r] = v;
        }
    }

    int capT = -1;   // last-layer capture timestep per lane
    if (w == LL - 1) {
        int len = lengths[bg * 16 + bi16];
        capT = ((len < 1) ? 1 : len) - 1;
    }

    const int laneoff = lane * 8;
    const int inbase  = (w == 0) ? X_HI : (H_HI + (w - 1) * 2048);
    const int inmask  = (w == 0) ? 1 : 3;
    const int ownhi   = H_HI + w * 2048;
    const int ownlo   = H_LO + w * 1024;
    const int wibase  = (quad >> 1) * 128 + bi16 * 8 + (quad & 1) * 4;

    // x staging constants (wave 0, lanes 0-47)
    const int xbb = lane / 3, xkg = lane - xbb * 3;
    const int xq   = (xkg == 2) ? 1 : 0;
    const int xoff = (xkg == 1) ? 4 : 0;
    const int xidx = xq * 128 + xbb * 8 + xoff;
    const bool xlane = (w == 0) && (lane < 48);

    auto stage_x = [&](const float4& xl, int t) {
        half4 h4;
        h4[0] = (_Float16)xl.x; h4[1] = (_Float16)xl.y;
        h4[2] = (_Float16)xl.z; h4[3] = (_Float16)xl.w;
        *(half4*)(lds16 + X_HI + ((t & 1) << 9) + xidx) = h4;
    };

    // stage x[0], x[1]
    if (xlane) {
        float4 x0 = *(const float4*)(x + (size_t)bg * 192 + lane * 4);
        float4 x1 = *(const float4*)(x + (size_t)BB * IN_DIM + (size_t)bg * 192 + lane * 4);
        stage_x(x0, 0);
        stage_x(x1, 1);
    }

    float hprev[8] = {0, 0, 0, 0, 0, 0, 0, 0};
    __syncthreads();   // flags + h0 + x0/x1 visible before self-timed phase

    auto substep = [&](int t) {
        // B-fragments: input (f16 hi only) + own h (hi+lo)
        half8 bxh = *(const half8*)(lds16 + inbase + ((t & inmask) << 9) + laneoff);
        half8 bhh = *(const half8*)(lds16 + ownhi + (((t + 3) & 3) << 9) + laneoff);
        half8 bhl = *(const half8*)(lds16 + ownlo + (((t + 1) & 1) << 9) + laneoff);

        f32x4 acc[8];
#pragma unroll
        for (int ct = 0; ct < 8; ct++) acc[ct] = biasreg[ct];

        // 24 MFMAs: r/z tiles 4 each; IN 1 each; HN 3 each
#pragma unroll
        for (int ct = 0; ct < 4; ct++) {
            MFMA_(Whi[ct * 2 + 0], bxh, acc[ct]);
            MFMA_(Whi[ct * 2 + 1], bhh, acc[ct]);
            MFMA_(Whi[ct * 2 + 1], bhl, acc[ct]);
            MFMA_(Wlo[ct],         bhh, acc[ct]);
        }
#pragma unroll
        for (int jt = 0; jt < 2; jt++) {
            MFMA_(Whi[8 + jt],  bxh, acc[4 + jt]);
            MFMA_(Whi[10 + jt], bhh, acc[6 + jt]);
            MFMA_(Whi[10 + jt], bhl, acc[6 + jt]);
            MFMA_(Wlo[4 + jt],  bhh, acc[6 + jt]);
        }

        // epilogue: r = rcp(1+exp2(accR)), z likewise,
        // n = 1 - 2*rcp(exp2(IN + r*HN)+1)  (scales pre-folded into W/b)
#pragma unroll
        for (int jt = 0; jt < 2; jt++) {
            f32x4 R = acc[0 + jt], Z = acc[2 + jt];
            f32x4 IN_ = acc[4 + jt], HN = acc[6 + jt];
            half4 h4, l4;
            float hv[4];
#pragma unroll
            for (int r = 0; r < 4; r++) {
                float rv = __builtin_amdgcn_rcpf(1.0f + __builtin_amdgcn_exp2f(R[r]));
                float zv = __builtin_amdgcn_rcpf(1.0f + __builtin_amdgcn_exp2f(Z[r]));
                float ea = __builtin_amdgcn_exp2f(fmaf(rv, HN[r], IN_[r]));
                float nv = fmaf(-2.0f, __builtin_amdgcn_rcpf(ea + 1.0f), 1.0f);
                float h  = fmaf(zv, hprev[jt * 4 + r] - nv, nv);
                hprev[jt * 4 + r] = h;
                _Float16 hh16 = (_Float16)h;
                h4[r] = hh16;
                l4[r] = (_Float16)(h - (float)hh16);
                hv[r] = h;
            }
            int wi = jt * 256 + wibase;
            *(half4*)(lds16 + ownhi + ((t & 3) << 9) + wi) = h4;
            *(half4*)(lds16 + ownlo + ((t & 1) << 9) + wi) = l4;
            if (w == LL - 1 && t == capT) {
                float4 o = make_float4(hv[0], hv[1], hv[2], hv[3]);
                *(float4*)(last + (size_t)(bg * 16 + bi16) * HH + jt * 16 + quad * 4) = o;
            }
        }
    };

    for (int t = 0; t < TT; t += 2) {
        // fwd sync: input panels for t, t+1 published by wave w-1
        if (w > 0) {
            while (__hip_atomic_load(&flagS[w - 1], __ATOMIC_ACQUIRE,
                                     __HIP_MEMORY_SCOPE_WORKGROUP) < t + 1)
                __builtin_amdgcn_s_sleep(1);
        }
        // bwd sync: writing t+1 reuses slot of t-3 — consumer must be done
        if (w < LL - 1) {
            while (__hip_atomic_load(&rflagS[w], __ATOMIC_ACQUIRE,
                                     __HIP_MEMORY_SCOPE_WORKGROUP) < t - 3)
                __builtin_amdgcn_s_sleep(1);
        }

        // wave 0: issue global x loads for t+2, t+3 early
        float4 xa0, xa1;
        bool dl0 = false, dl1 = false;
        if (xlane) {
            if (t + 2 < TT) {
                xa0 = *(const float4*)(x + (size_t)(t + 2) * BB * IN_DIM +
                                       (size_t)bg * 192 + lane * 4);
                dl0 = true;
            }
            if (t + 3 < TT) {
                xa1 = *(const float4*)(x + (size_t)(t + 3) * BB * IN_DIM +
                                       (size_t)bg * 192 + lane * 4);
                dl1 = true;
            }
        }

        substep(t);
        substep(t + 1);

        if (dl0) stage_x(xa0, t + 2);   // slot t&1 already read in substep(t)
        if (dl1) stage_x(xa1, t + 3);

        if (lane == 0) {
            // release: waits for this wave's DS ops (panel writes AND input
            // reads) to drain before publishing
            if (w < LL - 1)
                __hip_atomic_store(&flagS[w], t + 1, __ATOMIC_RELEASE,
                                   __HIP_MEMORY_SCOPE_WORKGROUP);
            if (w > 0)
                __hip_atomic_store(&rflagS[w - 1], t + 1, __ATOMIC_RELEASE,
                                   __HIP_MEMORY_SCOPE_WORKGROUP);
        }
    }
}

__global__ __launch_bounds__(256)
void fc_head(const float* __restrict__ last,
             const float* __restrict__ fcW,   // [C][H]
             const float* __restrict__ fcb,   // [C]
             float* __restrict__ out)         // [B][C]
{
    int b = blockIdx.x * blockDim.x + threadIdx.x;
    if (b >= BB) return;
    float lg[CC];
#pragma unroll
    for (int c = 0; c < CC; c++) lg[c] = fcb[c];
#pragma unroll
    for (int j = 0; j < HH; j++) {
        float h = last[(size_t)b * HH + j];
#pragma unroll
        for (int c = 0; c < CC; c++) lg[c] = fmaf(fcW[c * HH + j], h, lg[c]);
    }
    float m = lg[0];
#pragma unroll
    for (int c = 1; c < CC; c++) m = fmaxf(m, lg[c]);
    float s = 0.0f;
#pragma unroll
    for (int c = 0; c < CC; c++) s += __expf(lg[c] - m);
    float lse = m + logf(s);
#pragma unroll
    for (int c = 0; c < CC; c++) out[(size_t)b * CC + c] = lg[c] - lse;
}

extern "C" void kernel_launch(void* const* d_in, const int* in_sizes, int n_in,
                              void* d_out, int out_size, void* d_ws, size_t ws_size,
                              hipStream_t stream)
{
    const float* x    = (const float*)d_in[0];
    const float* Wih0 = (const float*)d_in[1];
    const float* Whh0 = (const float*)d_in[2];
    const float* bih0 = (const float*)d_in[3];
    const float* bhh0 = (const float*)d_in[4];
    const float* Wih  = (const float*)d_in[5];
    const float* Whh  = (const float*)d_in[6];
    const float* bih  = (const float*)d_in[7];
    const float* bhh  = (const float*)d_in[8];
    const float* fcW  = (const float*)d_in[9];
    const float* fcb  = (const float*)d_in[10];
    const int*   lens = (const int*)d_in[11];
    float* out = (float*)d_out;

    float* last = (float*)d_ws;   // [B][32] = 512 KB

    gru_fused_mfma<<<dim3(BB / 16), dim3(NTH), 0, stream>>>(
        x, Wih0, Whh0, bih0, bhh0, Wih, Whh, bih, bhh, lens, last);

    fc_head<<<dim3(BB / 256), dim3(256), 0, stream>>>(last, fcW, fcb, out);
}